// Round 11
// baseline (375.266 us; speedup 1.0000x reference)
//
#include <hip/hip_runtime.h>
#include <cstdint>
#include <cstddef>

namespace {

constexpr int kB    = 64;
constexpr int kN    = 1024;
constexpr int kE    = 655360;
constexpr int kEper = kE / kB;     // 10240
constexpr int kH    = 128;
constexpr int kK1   = 820;
constexpr int kK2   = 656;
constexpr int kM1   = kB * kN;     // 65536
constexpr int kM2   = kB * kK1;    // 52480
constexpr int kM3   = kB * kK2;    // 41984
constexpr int kRChunks = 16;       // readout row-chunks per graph

typedef __attribute__((ext_vector_type(8))) short bf16x8;
typedef __attribute__((ext_vector_type(4))) float f32x4;

__device__ inline ushort f2bf(float f) {            // fp32 -> bf16 RNE bits
  uint u = __float_as_uint(f);
  return (ushort)((u + 0x7fffu + ((u >> 16) & 1u)) >> 16);
}
__device__ inline float bf2f(ushort s) { return __uint_as_float(((uint)s) << 16); }

// inclusive block scan over 1024 threads: wave shfl-scan + 16-wavesum scan.
__device__ inline int block_scan_1024(int v, int* wsum /* LDS int[16] */) {
  const int lane = threadIdx.x & 63;
  const int w    = threadIdx.x >> 6;
#pragma unroll
  for (int off = 1; off < 64; off <<= 1) {
    const int n = __shfl_up(v, off);
    if (lane >= off) v += n;
  }
  if (lane == 63) wsum[w] = v;
  __syncthreads();
  if (w == 0) {
    int s = (lane < 16) ? wsum[lane] : 0;
#pragma unroll
    for (int off = 1; off < 16; off <<= 1) {
      const int n = __shfl_up(s, off);
      if (lane >= off) s += n;
    }
    if (lane < 16) wsum[lane] = s;
  }
  __syncthreads();
  if (w > 0) v += wsum[w - 1];
  return v;
}

// ================= prep: W^T hi/lo split + pw normalize =================
__global__ __launch_bounds__(256)
void prep_kernel(const float* __restrict__ Wl1, const float* __restrict__ Wr1,
                 const float* __restrict__ Wl2, const float* __restrict__ Wr2,
                 const float* __restrict__ pw1, const float* __restrict__ pw2,
                 ushort* __restrict__ W1h, ushort* __restrict__ W1l,
                 ushort* __restrict__ W2h, ushort* __restrict__ W2l,
                 float* __restrict__ pwn1, float* __restrict__ pwn2) {
  const int tid = threadIdx.x;
  if (blockIdx.x == 256) {
    __shared__ float sq[256];
    const float* pw = (tid < 128) ? pw1 : pw2;
    const int j = tid & 127;
    const float v = pw[j];
    sq[tid] = v * v;
    __syncthreads();
    const int base = (tid < 128) ? 0 : 128;
    float sum = 0.0f;
    for (int k = 0; k < 128; ++k) sum += sq[base + k];
    float* o = (tid < 128) ? pwn1 : pwn2;
    o[j] = v / sqrtf(sum);
    return;
  }
  const bool l2 = blockIdx.x >= 128;
  const int idx = (blockIdx.x & 127) * 256 + tid;   // 0..32767
  const int n = idx >> 8, k = idx & 255;
  const float* Wl = l2 ? Wl2 : Wl1;
  const float* Wr = l2 ? Wr2 : Wr1;
  const float w = (k < 128) ? Wl[k * kH + n] : Wr[(k - 128) * kH + n];
  const ushort h = f2bf(w);
  (l2 ? W2h : W1h)[n * 256 + k] = h;
  (l2 ? W2l : W1l)[n * 256 + k] = f2bf(w - bf2f(h));
}

// ================= layer-1 CSR build =================
__global__ void deg_kernel(const int* __restrict__ dst, int* __restrict__ deg) {
  int e = blockIdx.x * blockDim.x + threadIdx.x;
  if (e >= kE) return;
  atomicAdd(&deg[dst[e]], 1);
}

__global__ __launch_bounds__(1024)
void scan_kernel(const int* __restrict__ deg, int nloc,
                 int* __restrict__ off, int* __restrict__ cursor) {
  __shared__ int wsum[16];
  const int g = blockIdx.x, i = threadIdx.x;
  const int d = (i < nloc) ? deg[g * nloc + i] : 0;
  const int incl = block_scan_1024(d, wsum);
  if (i < nloc) {
    const int start = g * kEper + incl - d;    // exclusive scan
    off[g * nloc + i]    = start;
    cursor[g * nloc + i] = start;
  }
}

__global__ void fill1_kernel(const int* __restrict__ src, const int* __restrict__ dst,
                             int* __restrict__ cursor, int* __restrict__ ent) {
  int e = blockIdx.x * blockDim.x + threadIdx.x;
  if (e >= kE) return;
  const int pos = atomicAdd(&cursor[dst[e]], 1);
  ent[pos] = src[e];
}

// ---- ent2: layer-2 entries precomputed so gather2 has a single indirection ----
// ent2[p] = { src | keep<<30 , keep ? scoreBits : 0 }
__global__ void ent2prep_kernel(const int* __restrict__ ent,
                                const int2* __restrict__ aux,
                                int2* __restrict__ ent2) {
  int p = blockIdx.x * blockDim.x + threadIdx.x;
  if (p >= kE) return;
  const int s = ent[p];
  const int2 a = aux[s];
  ent2[p] = make_int2(s | (a.x << 30), a.x ? a.y : 0);
}

// guarded entry: past-end -> row 0 (valid memory; contribution masked).
__device__ inline int eg(const int* __restrict__ ent, int p, int o1) {
  return (p < o1) ? ent[p] : 0;
}
__device__ inline int2 eg2(const int2* __restrict__ ent, int p, int o1) {
  return (p < o1) ? ent[p] : make_int2(0, 0);     // keep=0, scale=0
}

// ================= layer-1 gather-mean: FULL wave per node =================
// The two 32-lane halves process interleaved entries of the SAME node
// (half h takes entries p+2i+h): 8 feature rows in flight per wave at
// depth-4 VGPR cost (R8 showed depth-8/half blows registers). Partial sums
// combined with shfl_xor(·,32). XCD swizzle: blockIdx&7 -> XCD, 8 graphs/XCD.
// npb = ceil(nloc/4) blocks per graph (4 waves/block = 4 nodes/block).
__global__ __launch_bounds__(256)
void gather1_kernel(const float* __restrict__ feat, const int* __restrict__ ent,
                    const int* __restrict__ off, const int* __restrict__ cursor,
                    float* __restrict__ aggout, int nloc, int npb) {
  const int xcd   = blockIdx.x & 7;
  const int local = blockIdx.x >> 3;
  const int gsub  = local / npb;
  const int graph = xcd * 8 + gsub;
  const int lane  = threadIdx.x & 63;
  const int h     = lane >> 5;                   // entry parity within pair
  const int l     = lane & 31;                   // feature quarter
  const int wid   = threadIdx.x >> 6;
  const int lnode = (local - gsub * npb) * 4 + wid;
  if (lnode >= nloc) return;
  const int node = graph * nloc + lnode;
  const int o0 = off[node], o1 = cursor[node];
  const float r = 1.0f / fmaxf((float)(o1 - o0), 1.0f);
  float4 acc = make_float4(0.f, 0.f, 0.f, 0.f);

  // half h owns entries o0 + 2*i + h; depth-4 per half = 8 rows in flight.
  int e[4], n[4];
  float4 v[4];
#pragma unroll
  for (int i = 0; i < 4; ++i) e[i] = eg(ent, o0 + 2 * i + h, o1);
#pragma unroll
  for (int i = 0; i < 4; ++i) v[i] = *(const float4*)(feat + (size_t)e[i] * kH + l * 4);
#pragma unroll
  for (int i = 0; i < 4; ++i) n[i] = eg(ent, o0 + 8 + 2 * i + h, o1);

  for (int p = o0; p < o1; p += 8) {
    int m[4];
    float4 w[4];
#pragma unroll
    for (int i = 0; i < 4; ++i) m[i] = eg(ent, p + 16 + 2 * i + h, o1);
#pragma unroll
    for (int i = 0; i < 4; ++i) w[i] = *(const float4*)(feat + (size_t)n[i] * kH + l * 4);
#pragma unroll
    for (int i = 0; i < 4; ++i) {
      const float s = (p + 2 * i + h < o1) ? 1.0f : 0.0f;
      acc.x += v[i].x * s; acc.y += v[i].y * s;
      acc.z += v[i].z * s; acc.w += v[i].w * s;
    }
#pragma unroll
    for (int i = 0; i < 4; ++i) { e[i] = n[i]; n[i] = m[i]; v[i] = w[i]; }
  }
  // combine the two halves (partner lane = lane ^ 32)
  acc.x += __shfl_xor(acc.x, 32);
  acc.y += __shfl_xor(acc.y, 32);
  acc.z += __shfl_xor(acc.z, 32);
  acc.w += __shfl_xor(acc.w, 32);
  if (h == 0)
    *(float4*)(aggout + (size_t)node * kH + l * 4) =
        make_float4(acc.x * r, acc.y * r, acc.z * r, acc.w * r);
}

// ================= layer-2 gather-mean: full wave per node, via ent2 ==========
__global__ __launch_bounds__(256)
void gather2_kernel(const float* __restrict__ feat, const int2* __restrict__ ent2,
                    const int* __restrict__ off, const int* __restrict__ cursor,
                    const int* __restrict__ perm,
                    float* __restrict__ aggout, int nloc, int npb) {
  const int xcd   = blockIdx.x & 7;
  const int local = blockIdx.x >> 3;
  const int gsub  = local / npb;
  const int graph = xcd * 8 + gsub;
  const int lane  = threadIdx.x & 63;
  const int h     = lane >> 5;
  const int l     = lane & 31;
  const int wid   = threadIdx.x >> 6;
  const int lnode = (local - gsub * npb) * 4 + wid;
  if (lnode >= nloc) return;
  const int node = graph * nloc + lnode;
  const int orig = perm[node];
  const int o0 = off[orig], o1 = cursor[orig];
  float4 acc = make_float4(0.f, 0.f, 0.f, 0.f);
  int cnt = 0;

  int2 e[4], n[4];
  float4 v[4];
#pragma unroll
  for (int i = 0; i < 4; ++i) e[i] = eg2(ent2, o0 + 2 * i + h, o1);
#pragma unroll
  for (int i = 0; i < 4; ++i)
    v[i] = *(const float4*)(feat + (size_t)(e[i].x & 0x3FFFFFFF) * kH + l * 4);
#pragma unroll
  for (int i = 0; i < 4; ++i) n[i] = eg2(ent2, o0 + 8 + 2 * i + h, o1);

  for (int p = o0; p < o1; p += 8) {
    int2 m[4];
    float4 w[4];
#pragma unroll
    for (int i = 0; i < 4; ++i) m[i] = eg2(ent2, p + 16 + 2 * i + h, o1);
#pragma unroll
    for (int i = 0; i < 4; ++i)
      w[i] = *(const float4*)(feat + (size_t)(n[i].x & 0x3FFFFFFF) * kH + l * 4);
#pragma unroll
    for (int i = 0; i < 4; ++i) {
      const bool valid = (p + 2 * i + h < o1);
      const int keep = valid ? ((e[i].x >> 30) & 1) : 0;
      cnt += keep;
      const float s = (valid && keep) ? __int_as_float(e[i].y) : 0.0f;
      acc.x += v[i].x * s; acc.y += v[i].y * s;
      acc.z += v[i].z * s; acc.w += v[i].w * s;
    }
#pragma unroll
    for (int i = 0; i < 4; ++i) { e[i] = n[i]; n[i] = m[i]; v[i] = w[i]; }
  }
  acc.x += __shfl_xor(acc.x, 32);
  acc.y += __shfl_xor(acc.y, 32);
  acc.z += __shfl_xor(acc.z, 32);
  acc.w += __shfl_xor(acc.w, 32);
  cnt   += __shfl_xor(cnt, 32);
  if (h == 0) {
    const float r = 1.0f / fmaxf((float)cnt, 1.0f);
    *(float4*)(aggout + (size_t)node * kH + l * 4) =
        make_float4(acc.x * r, acc.y * r, acc.z * r, acc.w * r);
  }
}

// ================= split-bf16 MFMA SAGE GEMM + fused score =================
// 64-row x 128-col block tile, 4 waves in 2x2, wave tile 32x64 (rt=2, ct=4).
__global__ __launch_bounds__(256)
void sage_gemm_mfma(const float* __restrict__ meanb, const float* __restrict__ xsrc,
                    const int* __restrict__ perm, const float* __restrict__ gsc,
                    const ushort* __restrict__ WTh, const ushort* __restrict__ WTl,
                    const float* __restrict__ bias, const float* __restrict__ pwn,
                    float* __restrict__ outp, float* __restrict__ scr) {
  __shared__ __align__(16) ushort aH[64][32];    // [row][k], 64 B row stride
  __shared__ __align__(16) ushort aL[64][32];
  __shared__ __align__(16) ushort wHs[128][32];  // [n][k] (= W^T)
  __shared__ __align__(16) ushort wLs[128][32];
  __shared__ float sdot[64][2];                  // [row][col-half] score partials
  const int tid  = threadIdx.x;
  const int wid  = tid >> 6;
  const int lane = tid & 63;
  const int quad = lane >> 4;
  const int l16  = lane & 15;
  const int rowbase = blockIdx.x * 64;
  const int wr = (wid >> 1) * 32;                // wave row offset (0/32)
  const int wc = (wid & 1) * 64;                 // wave col offset (0/64)

  f32x4 acc[2][4];
#pragma unroll
  for (int a = 0; a < 2; ++a)
#pragma unroll
    for (int b = 0; b < 4; ++b) acc[a][b] = (f32x4){0.f, 0.f, 0.f, 0.f};

  for (int s = 0; s < 8; ++s) {                  // 8 k-steps of 32 over K=256
    const bool ismean = s < 4;
    const float* sp = ismean ? meanb : xsrc;
    const int kbase = s * 32;
    const int kloc  = ismean ? kbase : kbase - 128;
    // ---- stage A (fp32 -> bf16 hi/lo): 64 rows x 32 k ----
#pragma unroll
    for (int i = 0; i < 2; ++i) {
      const int p   = tid + i * 256;
      const int row = p >> 3;
      const int k4  = (p & 7) * 4;
      const int grow = rowbase + row;
      int srow = grow; float scale = 1.0f;
      if (perm) { if (!ismean) { srow = perm[grow]; scale = gsc[grow]; } }
      const float4 v = *(const float4*)(sp + (size_t)srow * kH + kloc + k4);
      float f[4] = {v.x * scale, v.y * scale, v.z * scale, v.w * scale};
      ushort4 hv, lv;
      hv.x = f2bf(f[0]); lv.x = f2bf(f[0] - bf2f(hv.x));
      hv.y = f2bf(f[1]); lv.y = f2bf(f[1] - bf2f(hv.y));
      hv.z = f2bf(f[2]); lv.z = f2bf(f[2] - bf2f(hv.z));
      hv.w = f2bf(f[3]); lv.w = f2bf(f[3] - bf2f(hv.w));
      *(ushort4*)&aH[row][k4] = hv;
      *(ushort4*)&aL[row][k4] = lv;
    }
    // ---- stage W^T hi/lo: 128 n x 32 k ----
#pragma unroll
    for (int i = 0; i < 4; ++i) {
      const int p  = tid + i * 256;
      const int n  = p >> 3;
      const int k4 = (p & 7) * 4;
      *(ushort4*)&wHs[n][k4] = *(const ushort4*)(WTh + n * 256 + kbase + k4);
      *(ushort4*)&wLs[n][k4] = *(const ushort4*)(WTl + n * 256 + kbase + k4);
    }
    __syncthreads();
    bf16x8 afh[2], afl[2];
#pragma unroll
    for (int rt = 0; rt < 2; ++rt) {
      afh[rt] = *(const bf16x8*)&aH[wr + rt * 16 + l16][quad * 8];
      afl[rt] = *(const bf16x8*)&aL[wr + rt * 16 + l16][quad * 8];
    }
#pragma unroll
    for (int ct = 0; ct < 4; ++ct) {
      const bf16x8 bh = *(const bf16x8*)&wHs[wc + ct * 16 + l16][quad * 8];
      const bf16x8 bl = *(const bf16x8*)&wLs[wc + ct * 16 + l16][quad * 8];
#pragma unroll
      for (int rt = 0; rt < 2; ++rt) {
        acc[rt][ct] = __builtin_amdgcn_mfma_f32_16x16x32_bf16(afh[rt], bh, acc[rt][ct], 0, 0, 0);
        acc[rt][ct] = __builtin_amdgcn_mfma_f32_16x16x32_bf16(afh[rt], bl, acc[rt][ct], 0, 0, 0);
        acc[rt][ct] = __builtin_amdgcn_mfma_f32_16x16x32_bf16(afl[rt], bh, acc[rt][ct], 0, 0, 0);
      }
    }
    __syncthreads();
  }
  // ---- epilogue: bias + relu + store + fused score (64-col partial/wave) ----
  float bv[4], pwv[4];
#pragma unroll
  for (int ct = 0; ct < 4; ++ct) {
    const int col = wc + ct * 16 + l16;
    bv[ct]  = bias[col];
    pwv[ct] = pwn[col];
  }
  float dot[2][4];
#pragma unroll
  for (int rt = 0; rt < 2; ++rt)
#pragma unroll
    for (int reg = 0; reg < 4; ++reg) dot[rt][reg] = 0.0f;
#pragma unroll
  for (int ct = 0; ct < 4; ++ct) {
    const int col = wc + ct * 16 + l16;
#pragma unroll
    for (int rt = 0; rt < 2; ++rt) {
#pragma unroll
      for (int reg = 0; reg < 4; ++reg) {
        const int row = rowbase + wr + rt * 16 + quad * 4 + reg;
        const float o = fmaxf(acc[rt][ct][reg] + bv[ct], 0.0f);
        outp[(size_t)row * kH + col] = o;
        dot[rt][reg] += o * pwv[ct];
      }
    }
  }
#pragma unroll
  for (int rt = 0; rt < 2; ++rt) {
#pragma unroll
    for (int reg = 0; reg < 4; ++reg) {
      float d = dot[rt][reg];
      d += __shfl_xor(d, 1);
      d += __shfl_xor(d, 2);
      d += __shfl_xor(d, 4);
      d += __shfl_xor(d, 8);
      if (l16 == 0) sdot[wr + rt * 16 + quad * 4 + reg][wc >> 6] = d;
    }
  }
  __syncthreads();
  if (tid < 64) scr[rowbase + tid] = tanhf(sdot[tid][0] + sdot[tid][1]);
}

// ---- top-K rank phase: 4 chunk-blocks per graph, one thread per node ----
__global__ __launch_bounds__(256)
void rank_kernel(const float* __restrict__ scr, int n_per, int K,
                 int* __restrict__ kflag) {
  __shared__ __align__(16) float s[1024];
  const int g     = blockIdx.x >> 2;
  const int chunk = blockIdx.x & 3;
  const int tid   = threadIdx.x;
  for (int i = tid; i < 1024; i += 256)
    s[i] = (i < n_per) ? scr[g * n_per + i] : -3e30f;   // pad never outranks
  __syncthreads();
  const int i0 = chunk * 256 + tid;
  if (i0 >= n_per) return;
  const float mys = s[i0];
  int rank = 0;
  for (int j = 0; j < 1024; j += 4) {
    const float4 sj = *(const float4*)&s[j];
    rank += (sj.x > mys) || (sj.x == mys && (j + 0) < i0);
    rank += (sj.y > mys) || (sj.y == mys && (j + 1) < i0);
    rank += (sj.z > mys) || (sj.z == mys && (j + 2) < i0);
    rank += (sj.w > mys) || (sj.w == mys && (j + 3) < i0);
  }
  kflag[g * n_per + i0] = (rank < K) ? 1 : 0;
}

// ---- compaction: per-graph scan of keep flags; aux={keep,score} for layer1 ----
__global__ __launch_bounds__(1024)
void compact_kernel(const float* __restrict__ scr, const int* __restrict__ kflag,
                    int n_per, int K, int* __restrict__ perm,
                    float* __restrict__ gsc, int2* __restrict__ aux) {
  __shared__ int wsum[16];
  const int g = blockIdx.x, i = threadIdx.x;
  const int keep = (i < n_per) ? kflag[g * n_per + i] : 0;
  const int incl = block_scan_1024(keep, wsum);
  if (i < n_per) {
    const float sc = scr[g * n_per + i];
    if (keep) {
      const int pos = incl - 1;
      perm[g * K + pos] = g * n_per + i;
      gsc[g * K + pos]  = sc;
    }
    if (aux) aux[g * n_per + i] = make_int2(keep, __float_as_int(sc));
  }
}

// ---- readout stage 1: per-(graph, row-chunk) partial mean/max over gated rows ----
__global__ __launch_bounds__(256)
void readout_part(const float* __restrict__ h, const int* __restrict__ perm,
                  const float* __restrict__ gsc, int K,
                  float* __restrict__ psum, float* __restrict__ pmax) {
  const int g     = blockIdx.x >> 4;
  const int chunk = blockIdx.x & (kRChunks - 1);
  const int j     = threadIdx.x & 127;
  const int part  = threadIdx.x >> 7;            // 2 parts
  const int rows  = (K + kRChunks - 1) / kRChunks;
  const int r0 = chunk * rows;
  const int r1 = min(r0 + rows, K);
  float sum = 0.0f, mx = -1e30f;
  for (int r = r0 + part; r < r1; r += 2) {
    const int   row = perm[g * K + r];
    const float sc  = gsc[g * K + r];
    const float v   = h[(size_t)row * kH + j] * sc;
    sum += v;
    mx = fmaxf(mx, v);
  }
  __shared__ float ss[2][128], sm[2][128];
  ss[part][j] = sum;
  sm[part][j] = mx;
  __syncthreads();
  if (part == 0) {
    sum += ss[1][j];
    mx = fmaxf(mx, sm[1][j]);
    psum[(size_t)blockIdx.x * 128 + j] = sum;
    pmax[(size_t)blockIdx.x * 128 + j] = mx;
  }
}

// ---- fused: combine readout chunks (both layers) + 2-layer MLP head ----
__global__ __launch_bounds__(128)
void final_mlp(const float* __restrict__ ps1, const float* __restrict__ pm1,
               const float* __restrict__ ps2, const float* __restrict__ pm2,
               const float* __restrict__ fW1, const float* __restrict__ fb1,
               const float* __restrict__ fW2, const float* __restrict__ fb2,
               float* __restrict__ out) {
  __shared__ float xx[256];
  __shared__ float z[128];
  const int g = blockIdx.x, tid = threadIdx.x;
  float s1 = 0.f, m1 = -1e30f, s2 = 0.f, m2 = -1e30f;
#pragma unroll
  for (int c = 0; c < kRChunks; ++c) {
    s1 += ps1[(size_t)(g * kRChunks + c) * 128 + tid];
    m1 = fmaxf(m1, pm1[(size_t)(g * kRChunks + c) * 128 + tid]);
    s2 += ps2[(size_t)(g * kRChunks + c) * 128 + tid];
    m2 = fmaxf(m2, pm2[(size_t)(g * kRChunks + c) * 128 + tid]);
  }
  xx[tid]       = s1 / (float)kK1 + s2 / (float)kK2;
  xx[tid + 128] = m1 + m2;
  __syncthreads();
  float a = fb1[tid];
  for (int k = 0; k < 256; ++k) a += xx[k] * fW1[k * 128 + tid];
  z[tid] = fmaxf(a, 0.0f);
  __syncthreads();
  if (tid < 10) {
    float o = fb2[tid];
    for (int k = 0; k < 128; ++k) o += z[k] * fW2[k * 10 + tid];
    out[g * 10 + tid] = o;
  }
}

}  // namespace

extern "C" void kernel_launch(void* const* d_in, const int* in_sizes, int n_in,
                              void* d_out, int out_size, void* d_ws, size_t ws_size,
                              hipStream_t stream) {
  const float* x   = (const float*)d_in[0];
  const int*   ei  = (const int*)d_in[1];
  const float* Wl1 = (const float*)d_in[3];
  const float* bl1 = (const float*)d_in[4];
  const float* Wr1 = (const float*)d_in[5];
  const float* Wl2 = (const float*)d_in[6];
  const float* bl2 = (const float*)d_in[7];
  const float* Wr2 = (const float*)d_in[8];
  const float* pw1 = (const float*)d_in[9];
  const float* pw2 = (const float*)d_in[10];
  const float* fW1 = (const float*)d_in[11];
  const float* fb1 = (const float*)d_in[12];
  const float* fW2 = (const float*)d_in[13];
  const float* fb2 = (const float*)d_in[14];
  const int* src = ei;
  const int* dst = ei + kE;
  (void)in_sizes; (void)n_in; (void)out_size; (void)ws_size;

  char* wsb = (char*)d_ws;
  size_t off_b = 0;
  auto alloc = [&](size_t bytes) {
    void* p = wsb + off_b;
    off_b += (bytes + 255) & ~(size_t)255;
    return p;
  };
  float* bufA = (float*)alloc((size_t)kM1 * kH * 4);  // mean1 -> mean2
  float* bufB = (float*)alloc((size_t)kM1 * kH * 4);  // h1
  float* bufC = (float*)alloc((size_t)kM2 * kH * 4);  // h2
  int*   deg  = (int*)alloc((size_t)kM1 * 4);
  int*   coff = (int*)alloc((size_t)kM1 * 4);
  int*   ccur = (int*)alloc((size_t)kM1 * 4);
  int*   ent  = (int*)alloc((size_t)kE * 4);
  int2*  ent2 = (int2*)alloc((size_t)kE * 8);
  float* scr  = (float*)alloc((size_t)kM1 * 4);
  int*   kflag= (int*)alloc((size_t)kM1 * 4);
  int2*  aux  = (int2*)alloc((size_t)kM1 * 8);
  int*   perm1= (int*)alloc((size_t)kM2 * 4);
  float* gsc1 = (float*)alloc((size_t)kM2 * 4);
  int*   perm2= (int*)alloc((size_t)kM3 * 4);
  float* gsc2 = (float*)alloc((size_t)kM3 * 4);
  float* psum1= (float*)alloc((size_t)kB * kRChunks * 128 * 4);
  float* pmax1= (float*)alloc((size_t)kB * kRChunks * 128 * 4);
  float* psum2= (float*)alloc((size_t)kB * kRChunks * 128 * 4);
  float* pmax2= (float*)alloc((size_t)kB * kRChunks * 128 * 4);
  ushort* wt1h = (ushort*)alloc((size_t)128 * 256 * 2);
  ushort* wt1l = (ushort*)alloc((size_t)128 * 256 * 2);
  ushort* wt2h = (ushort*)alloc((size_t)128 * 256 * 2);
  ushort* wt2l = (ushort*)alloc((size_t)128 * 256 * 2);
  float* pwn1 = (float*)alloc(128 * 4);
  float* pwn2 = (float*)alloc(128 * 4);

  prep_kernel<<<257, 256, 0, stream>>>(Wl1, Wr1, Wl2, Wr2, pw1, pw2,
                                       wt1h, wt1l, wt2h, wt2l, pwn1, pwn2);

  const int npb1 = kN / 4;             // 256 (4 nodes/block)
  const int npb2 = (kK1 + 3) / 4;      // 205

  // ---------------- layer 1 ----------------
  hipMemsetAsync(deg, 0, (size_t)kM1 * 4, stream);
  deg_kernel<<<kE / 256, 256, 0, stream>>>(dst, deg);
  scan_kernel<<<kB, 1024, 0, stream>>>(deg, kN, coff, ccur);
  fill1_kernel<<<kE / 256, 256, 0, stream>>>(src, dst, ccur, ent);
  gather1_kernel<<<64 * npb1, 256, 0, stream>>>(x, ent, coff, ccur, bufA, kN, npb1);
  sage_gemm_mfma<<<kM1 / 64, 256, 0, stream>>>(bufA, x, nullptr, nullptr,
                                               wt1h, wt1l, bl1, pwn1, bufB, scr);
  rank_kernel<<<kB * 4, 256, 0, stream>>>(scr, kN, kK1, kflag);
  compact_kernel<<<kB, 1024, 0, stream>>>(scr, kflag, kN, kK1, perm1, gsc1, aux);
  readout_part<<<kB * kRChunks, 256, 0, stream>>>(bufB, perm1, gsc1, kK1, psum1, pmax1);

  // ---------------- layer 2 (reuses layer-1 CSR; ent2 folds aux in) ----------------
  ent2prep_kernel<<<kE / 256, 256, 0, stream>>>(ent, aux, ent2);
  gather2_kernel<<<64 * npb2, 256, 0, stream>>>(bufB, ent2, coff, ccur, perm1,
                                                bufA, kK1, npb2);
  sage_gemm_mfma<<<kM2 / 64, 256, 0, stream>>>(bufA, bufB, perm1, gsc1,
                                               wt2h, wt2l, bl2, pwn2, bufC, scr);
  rank_kernel<<<kB * 4, 256, 0, stream>>>(scr, kK1, kK2, kflag);
  compact_kernel<<<kB, 1024, 0, stream>>>(scr, kflag, kK1, kK2, perm2, gsc2, nullptr);
  readout_part<<<kB * kRChunks, 256, 0, stream>>>(bufC, perm2, gsc2, kK2, psum2, pmax2);

  // ---------------- head ----------------
  final_mlp<<<kB, 128, 0, stream>>>(psum1, pmax1, psum2, pmax2,
                                    fW1, fb1, fW2, fb2, (float*)d_out);
}

// Round 12
// 367.643 us; speedup vs baseline: 1.0207x; 1.0207x over previous
//
#include <hip/hip_runtime.h>
#include <cstdint>
#include <cstddef>

namespace {

constexpr int kB    = 64;
constexpr int kN    = 1024;
constexpr int kE    = 655360;
constexpr int kEper = kE / kB;     // 10240
constexpr int kH    = 128;
constexpr int kK1   = 820;
constexpr int kK2   = 656;
constexpr int kM1   = kB * kN;     // 65536
constexpr int kM2   = kB * kK1;    // 52480
constexpr int kM3   = kB * kK2;    // 41984
constexpr int kRChunks = 16;       // readout row-chunks per graph

typedef __attribute__((ext_vector_type(8))) short bf16x8;
typedef __attribute__((ext_vector_type(4))) float f32x4;

__device__ inline ushort f2bf(float f) {            // fp32 -> bf16 RNE bits
  uint u = __float_as_uint(f);
  return (ushort)((u + 0x7fffu + ((u >> 16) & 1u)) >> 16);
}
__device__ inline float bf2f(ushort s) { return __uint_as_float(((uint)s) << 16); }

// inclusive block scan over 1024 threads: wave shfl-scan + 16-wavesum scan.
__device__ inline int block_scan_1024(int v, int* wsum /* LDS int[16] */) {
  const int lane = threadIdx.x & 63;
  const int w    = threadIdx.x >> 6;
#pragma unroll
  for (int off = 1; off < 64; off <<= 1) {
    const int n = __shfl_up(v, off);
    if (lane >= off) v += n;
  }
  if (lane == 63) wsum[w] = v;
  __syncthreads();
  if (w == 0) {
    int s = (lane < 16) ? wsum[lane] : 0;
#pragma unroll
    for (int off = 1; off < 16; off <<= 1) {
      const int n = __shfl_up(s, off);
      if (lane >= off) s += n;
    }
    if (lane < 16) wsum[lane] = s;
  }
  __syncthreads();
  if (w > 0) v += wsum[w - 1];
  return v;
}

// ================= prep: W^T hi/lo split + pw normalize =================
__global__ __launch_bounds__(256)
void prep_kernel(const float* __restrict__ Wl1, const float* __restrict__ Wr1,
                 const float* __restrict__ Wl2, const float* __restrict__ Wr2,
                 const float* __restrict__ pw1, const float* __restrict__ pw2,
                 ushort* __restrict__ W1h, ushort* __restrict__ W1l,
                 ushort* __restrict__ W2h, ushort* __restrict__ W2l,
                 float* __restrict__ pwn1, float* __restrict__ pwn2) {
  const int tid = threadIdx.x;
  if (blockIdx.x == 256) {
    __shared__ float sq[256];
    const float* pw = (tid < 128) ? pw1 : pw2;
    const int j = tid & 127;
    const float v = pw[j];
    sq[tid] = v * v;
    __syncthreads();
    const int base = (tid < 128) ? 0 : 128;
    float sum = 0.0f;
    for (int k = 0; k < 128; ++k) sum += sq[base + k];
    float* o = (tid < 128) ? pwn1 : pwn2;
    o[j] = v / sqrtf(sum);
    return;
  }
  const bool l2 = blockIdx.x >= 128;
  const int idx = (blockIdx.x & 127) * 256 + tid;   // 0..32767
  const int n = idx >> 8, k = idx & 255;
  const float* Wl = l2 ? Wl2 : Wl1;
  const float* Wr = l2 ? Wr2 : Wr1;
  const float w = (k < 128) ? Wl[k * kH + n] : Wr[(k - 128) * kH + n];
  const ushort h = f2bf(w);
  (l2 ? W2h : W1h)[n * 256 + k] = h;
  (l2 ? W2l : W1l)[n * 256 + k] = f2bf(w - bf2f(h));
}

// ================= layer-1 CSR build =================
__global__ void deg_kernel(const int* __restrict__ dst, int* __restrict__ deg) {
  int e = blockIdx.x * blockDim.x + threadIdx.x;
  if (e >= kE) return;
  atomicAdd(&deg[dst[e]], 1);
}

__global__ __launch_bounds__(1024)
void scan_kernel(const int* __restrict__ deg, int nloc,
                 int* __restrict__ off, int* __restrict__ cursor) {
  __shared__ int wsum[16];
  const int g = blockIdx.x, i = threadIdx.x;
  const int d = (i < nloc) ? deg[g * nloc + i] : 0;
  const int incl = block_scan_1024(d, wsum);
  if (i < nloc) {
    const int start = g * kEper + incl - d;    // exclusive scan
    off[g * nloc + i]    = start;
    cursor[g * nloc + i] = start;
  }
}

__global__ void fill1_kernel(const int* __restrict__ src, const int* __restrict__ dst,
                             int* __restrict__ cursor, int* __restrict__ ent) {
  int e = blockIdx.x * blockDim.x + threadIdx.x;
  if (e >= kE) return;
  const int pos = atomicAdd(&cursor[dst[e]], 1);
  ent[pos] = src[e];
}

// ---- ent2: layer-2 entries precomputed so gather2 has a single indirection ----
// ent2[p] = { src | keep<<30 , keep ? scoreBits : 0 }
__global__ void ent2prep_kernel(const int* __restrict__ ent,
                                const int2* __restrict__ aux,
                                int2* __restrict__ ent2) {
  int p = blockIdx.x * blockDim.x + threadIdx.x;
  if (p >= kE) return;
  const int s = ent[p];
  const int2 a = aux[s];
  ent2[p] = make_int2(s | (a.x << 30), a.x ? a.y : 0);
}

// guarded entry loads, NON-TEMPORAL (streamed once, zero reuse — keep out of L2;
// L2 capacity is the scarce resource for the feature rows: 8 graphs x 512 KB
// = full 4 MB XCD L2).  Past-end -> row 0 (valid memory; contribution masked).
__device__ inline int eg(const int* __restrict__ ent, int p, int o1) {
  return (p < o1) ? __builtin_nontemporal_load(ent + p) : 0;
}
__device__ inline int2 eg2(const int2* __restrict__ ent, int p, int o1) {
  if (p < o1) {
    const long long raw = __builtin_nontemporal_load((const long long*)ent + p);
    int2 r;
    r.x = (int)(raw & 0xFFFFFFFFll);
    r.y = (int)(raw >> 32);
    return r;
  }
  return make_int2(0, 0);                        // keep=0, scale=0
}

// ================= layer-1 gather-mean (R10 shape: half-wave/node, depth-4) ====
// Half-wave per node (lanes 0-31 node A, 32-63 node B), float4/lane.
// XCD swizzle: blockIdx&7 -> XCD, 8 graphs/XCD. npb = nloc/8 blocks per graph.
// depth-4 is the measured optimum (R8 depth-8: VGPR 68 / occupancy 26% regressed;
// R11 full-wave/node: +VALU overhead regressed).
// aggout stores are non-temporal: written once, read later by GEMM — don't
// let the 4 MB write stream evict feature rows from L2.
__global__ __launch_bounds__(256)
void gather1_kernel(const float* __restrict__ feat, const int* __restrict__ ent,
                    const int* __restrict__ off, const int* __restrict__ cursor,
                    float* __restrict__ aggout, int nloc, int npb) {
  const int xcd   = blockIdx.x & 7;
  const int local = blockIdx.x >> 3;
  const int gsub  = local / npb;
  const int graph = xcd * 8 + gsub;
  const int lane  = threadIdx.x & 63;
  const int h     = lane >> 5;
  const int l     = lane & 31;
  const int wid   = threadIdx.x >> 6;
  const int lnode = (local - gsub * npb) * 8 + wid * 2 + h;
  if (lnode >= nloc) return;
  const int node = graph * nloc + lnode;
  const int o0 = off[node], o1 = cursor[node];
  const float r = 1.0f / fmaxf((float)(o1 - o0), 1.0f);
  float4 acc = make_float4(0.f, 0.f, 0.f, 0.f);

  int e[4], n[4];
  float4 v[4];
#pragma unroll
  for (int i = 0; i < 4; ++i) e[i] = eg(ent, o0 + i, o1);
#pragma unroll
  for (int i = 0; i < 4; ++i) v[i] = *(const float4*)(feat + (size_t)e[i] * kH + l * 4);
#pragma unroll
  for (int i = 0; i < 4; ++i) n[i] = eg(ent, o0 + 4 + i, o1);

  for (int p = o0; p < o1; p += 4) {
    int m[4];
    float4 w[4];
#pragma unroll
    for (int i = 0; i < 4; ++i) m[i] = eg(ent, p + 8 + i, o1);
#pragma unroll
    for (int i = 0; i < 4; ++i) w[i] = *(const float4*)(feat + (size_t)n[i] * kH + l * 4);
#pragma unroll
    for (int i = 0; i < 4; ++i) {
      const float s = (p + i < o1) ? 1.0f : 0.0f;
      acc.x += v[i].x * s; acc.y += v[i].y * s;
      acc.z += v[i].z * s; acc.w += v[i].w * s;
    }
#pragma unroll
    for (int i = 0; i < 4; ++i) { e[i] = n[i]; n[i] = m[i]; v[i] = w[i]; }
  }
  const f32x4 res = {acc.x * r, acc.y * r, acc.z * r, acc.w * r};
  __builtin_nontemporal_store(res, (f32x4*)(aggout + (size_t)node * kH + l * 4));
}

// ================= layer-2 gather-mean over layer-1 CSR via ent2 =================
__global__ __launch_bounds__(256)
void gather2_kernel(const float* __restrict__ feat, const int2* __restrict__ ent2,
                    const int* __restrict__ off, const int* __restrict__ cursor,
                    const int* __restrict__ perm,
                    float* __restrict__ aggout, int nloc, int npb) {
  const int xcd   = blockIdx.x & 7;
  const int local = blockIdx.x >> 3;
  const int gsub  = local / npb;
  const int graph = xcd * 8 + gsub;
  const int lane  = threadIdx.x & 63;
  const int h     = lane >> 5;
  const int l     = lane & 31;
  const int wid   = threadIdx.x >> 6;
  const int lnode = (local - gsub * npb) * 8 + wid * 2 + h;
  if (lnode >= nloc) return;
  const int node = graph * nloc + lnode;
  const int orig = perm[node];
  const int o0 = off[orig], o1 = cursor[orig];
  float4 acc = make_float4(0.f, 0.f, 0.f, 0.f);
  int cnt = 0;

  int2 e[4], n[4];
  float4 v[4];
#pragma unroll
  for (int i = 0; i < 4; ++i) e[i] = eg2(ent2, o0 + i, o1);
#pragma unroll
  for (int i = 0; i < 4; ++i)
    v[i] = *(const float4*)(feat + (size_t)(e[i].x & 0x3FFFFFFF) * kH + l * 4);
#pragma unroll
  for (int i = 0; i < 4; ++i) n[i] = eg2(ent2, o0 + 4 + i, o1);

  for (int p = o0; p < o1; p += 4) {
    int2 m[4];
    float4 w[4];
#pragma unroll
    for (int i = 0; i < 4; ++i) m[i] = eg2(ent2, p + 8 + i, o1);
#pragma unroll
    for (int i = 0; i < 4; ++i)
      w[i] = *(const float4*)(feat + (size_t)(n[i].x & 0x3FFFFFFF) * kH + l * 4);
#pragma unroll
    for (int i = 0; i < 4; ++i) {
      const bool valid = (p + i < o1);
      const int keep = valid ? ((e[i].x >> 30) & 1) : 0;
      cnt += keep;
      const float s = (valid && keep) ? __int_as_float(e[i].y) : 0.0f;
      acc.x += v[i].x * s; acc.y += v[i].y * s;
      acc.z += v[i].z * s; acc.w += v[i].w * s;
    }
#pragma unroll
    for (int i = 0; i < 4; ++i) { e[i] = n[i]; n[i] = m[i]; v[i] = w[i]; }
  }
  const float r = 1.0f / fmaxf((float)cnt, 1.0f);
  const f32x4 res = {acc.x * r, acc.y * r, acc.z * r, acc.w * r};
  __builtin_nontemporal_store(res, (f32x4*)(aggout + (size_t)node * kH + l * 4));
}

// ================= split-bf16 MFMA SAGE GEMM + fused score =================
// 64-row x 128-col block tile, 4 waves in 2x2, wave tile 32x64 (rt=2, ct=4).
__global__ __launch_bounds__(256)
void sage_gemm_mfma(const float* __restrict__ meanb, const float* __restrict__ xsrc,
                    const int* __restrict__ perm, const float* __restrict__ gsc,
                    const ushort* __restrict__ WTh, const ushort* __restrict__ WTl,
                    const float* __restrict__ bias, const float* __restrict__ pwn,
                    float* __restrict__ outp, float* __restrict__ scr) {
  __shared__ __align__(16) ushort aH[64][32];    // [row][k], 64 B row stride
  __shared__ __align__(16) ushort aL[64][32];
  __shared__ __align__(16) ushort wHs[128][32];  // [n][k] (= W^T)
  __shared__ __align__(16) ushort wLs[128][32];
  __shared__ float sdot[64][2];                  // [row][col-half] score partials
  const int tid  = threadIdx.x;
  const int wid  = tid >> 6;
  const int lane = tid & 63;
  const int quad = lane >> 4;
  const int l16  = lane & 15;
  const int rowbase = blockIdx.x * 64;
  const int wr = (wid >> 1) * 32;                // wave row offset (0/32)
  const int wc = (wid & 1) * 64;                 // wave col offset (0/64)

  f32x4 acc[2][4];
#pragma unroll
  for (int a = 0; a < 2; ++a)
#pragma unroll
    for (int b = 0; b < 4; ++b) acc[a][b] = (f32x4){0.f, 0.f, 0.f, 0.f};

  for (int s = 0; s < 8; ++s) {                  // 8 k-steps of 32 over K=256
    const bool ismean = s < 4;
    const float* sp = ismean ? meanb : xsrc;
    const int kbase = s * 32;
    const int kloc  = ismean ? kbase : kbase - 128;
    // ---- stage A (fp32 -> bf16 hi/lo): 64 rows x 32 k ----
#pragma unroll
    for (int i = 0; i < 2; ++i) {
      const int p   = tid + i * 256;
      const int row = p >> 3;
      const int k4  = (p & 7) * 4;
      const int grow = rowbase + row;
      int srow = grow; float scale = 1.0f;
      if (perm) { if (!ismean) { srow = perm[grow]; scale = gsc[grow]; } }
      const float4 v = *(const float4*)(sp + (size_t)srow * kH + kloc + k4);
      float f[4] = {v.x * scale, v.y * scale, v.z * scale, v.w * scale};
      ushort4 hv, lv;
      hv.x = f2bf(f[0]); lv.x = f2bf(f[0] - bf2f(hv.x));
      hv.y = f2bf(f[1]); lv.y = f2bf(f[1] - bf2f(hv.y));
      hv.z = f2bf(f[2]); lv.z = f2bf(f[2] - bf2f(hv.z));
      hv.w = f2bf(f[3]); lv.w = f2bf(f[3] - bf2f(hv.w));
      *(ushort4*)&aH[row][k4] = hv;
      *(ushort4*)&aL[row][k4] = lv;
    }
    // ---- stage W^T hi/lo: 128 n x 32 k ----
#pragma unroll
    for (int i = 0; i < 4; ++i) {
      const int p  = tid + i * 256;
      const int n  = p >> 3;
      const int k4 = (p & 7) * 4;
      *(ushort4*)&wHs[n][k4] = *(const ushort4*)(WTh + n * 256 + kbase + k4);
      *(ushort4*)&wLs[n][k4] = *(const ushort4*)(WTl + n * 256 + kbase + k4);
    }
    __syncthreads();
    bf16x8 afh[2], afl[2];
#pragma unroll
    for (int rt = 0; rt < 2; ++rt) {
      afh[rt] = *(const bf16x8*)&aH[wr + rt * 16 + l16][quad * 8];
      afl[rt] = *(const bf16x8*)&aL[wr + rt * 16 + l16][quad * 8];
    }
#pragma unroll
    for (int ct = 0; ct < 4; ++ct) {
      const bf16x8 bh = *(const bf16x8*)&wHs[wc + ct * 16 + l16][quad * 8];
      const bf16x8 bl = *(const bf16x8*)&wLs[wc + ct * 16 + l16][quad * 8];
#pragma unroll
      for (int rt = 0; rt < 2; ++rt) {
        acc[rt][ct] = __builtin_amdgcn_mfma_f32_16x16x32_bf16(afh[rt], bh, acc[rt][ct], 0, 0, 0);
        acc[rt][ct] = __builtin_amdgcn_mfma_f32_16x16x32_bf16(afh[rt], bl, acc[rt][ct], 0, 0, 0);
        acc[rt][ct] = __builtin_amdgcn_mfma_f32_16x16x32_bf16(afl[rt], bh, acc[rt][ct], 0, 0, 0);
      }
    }
    __syncthreads();
  }
  // ---- epilogue: bias + relu + store + fused score (64-col partial/wave) ----
  float bv[4], pwv[4];
#pragma unroll
  for (int ct = 0; ct < 4; ++ct) {
    const int col = wc + ct * 16 + l16;
    bv[ct]  = bias[col];
    pwv[ct] = pwn[col];
  }
  float dot[2][4];
#pragma unroll
  for (int rt = 0; rt < 2; ++rt)
#pragma unroll
    for (int reg = 0; reg < 4; ++reg) dot[rt][reg] = 0.0f;
#pragma unroll
  for (int ct = 0; ct < 4; ++ct) {
    const int col = wc + ct * 16 + l16;
#pragma unroll
    for (int rt = 0; rt < 2; ++rt) {
#pragma unroll
      for (int reg = 0; reg < 4; ++reg) {
        const int row = rowbase + wr + rt * 16 + quad * 4 + reg;
        const float o = fmaxf(acc[rt][ct][reg] + bv[ct], 0.0f);
        outp[(size_t)row * kH + col] = o;
        dot[rt][reg] += o * pwv[ct];
      }
    }
  }
#pragma unroll
  for (int rt = 0; rt < 2; ++rt) {
#pragma unroll
    for (int reg = 0; reg < 4; ++reg) {
      float d = dot[rt][reg];
      d += __shfl_xor(d, 1);
      d += __shfl_xor(d, 2);
      d += __shfl_xor(d, 4);
      d += __shfl_xor(d, 8);
      if (l16 == 0) sdot[wr + rt * 16 + quad * 4 + reg][wc >> 6] = d;
    }
  }
  __syncthreads();
  if (tid < 64) scr[rowbase + tid] = tanhf(sdot[tid][0] + sdot[tid][1]);
}

// ---- top-K rank phase: 4 chunk-blocks per graph, one thread per node ----
__global__ __launch_bounds__(256)
void rank_kernel(const float* __restrict__ scr, int n_per, int K,
                 int* __restrict__ kflag) {
  __shared__ __align__(16) float s[1024];
  const int g     = blockIdx.x >> 2;
  const int chunk = blockIdx.x & 3;
  const int tid   = threadIdx.x;
  for (int i = tid; i < 1024; i += 256)
    s[i] = (i < n_per) ? scr[g * n_per + i] : -3e30f;   // pad never outranks
  __syncthreads();
  const int i0 = chunk * 256 + tid;
  if (i0 >= n_per) return;
  const float mys = s[i0];
  int rank = 0;
  for (int j = 0; j < 1024; j += 4) {
    const float4 sj = *(const float4*)&s[j];
    rank += (sj.x > mys) || (sj.x == mys && (j + 0) < i0);
    rank += (sj.y > mys) || (sj.y == mys && (j + 1) < i0);
    rank += (sj.z > mys) || (sj.z == mys && (j + 2) < i0);
    rank += (sj.w > mys) || (sj.w == mys && (j + 3) < i0);
  }
  kflag[g * n_per + i0] = (rank < K) ? 1 : 0;
}

// ---- compaction: per-graph scan of keep flags; aux={keep,score} for layer1 ----
__global__ __launch_bounds__(1024)
void compact_kernel(const float* __restrict__ scr, const int* __restrict__ kflag,
                    int n_per, int K, int* __restrict__ perm,
                    float* __restrict__ gsc, int2* __restrict__ aux) {
  __shared__ int wsum[16];
  const int g = blockIdx.x, i = threadIdx.x;
  const int keep = (i < n_per) ? kflag[g * n_per + i] : 0;
  const int incl = block_scan_1024(keep, wsum);
  if (i < n_per) {
    const float sc = scr[g * n_per + i];
    if (keep) {
      const int pos = incl - 1;
      perm[g * K + pos] = g * n_per + i;
      gsc[g * K + pos]  = sc;
    }
    if (aux) aux[g * n_per + i] = make_int2(keep, __float_as_int(sc));
  }
}

// ---- readout stage 1: per-(graph, row-chunk) partial mean/max over gated rows ----
__global__ __launch_bounds__(256)
void readout_part(const float* __restrict__ h, const int* __restrict__ perm,
                  const float* __restrict__ gsc, int K,
                  float* __restrict__ psum, float* __restrict__ pmax) {
  const int g     = blockIdx.x >> 4;
  const int chunk = blockIdx.x & (kRChunks - 1);
  const int j     = threadIdx.x & 127;
  const int part  = threadIdx.x >> 7;            // 2 parts
  const int rows  = (K + kRChunks - 1) / kRChunks;
  const int r0 = chunk * rows;
  const int r1 = min(r0 + rows, K);
  float sum = 0.0f, mx = -1e30f;
  for (int r = r0 + part; r < r1; r += 2) {
    const int   row = perm[g * K + r];
    const float sc  = gsc[g * K + r];
    const float v   = h[(size_t)row * kH + j] * sc;
    sum += v;
    mx = fmaxf(mx, v);
  }
  __shared__ float ss[2][128], sm[2][128];
  ss[part][j] = sum;
  sm[part][j] = mx;
  __syncthreads();
  if (part == 0) {
    sum += ss[1][j];
    mx = fmaxf(mx, sm[1][j]);
    psum[(size_t)blockIdx.x * 128 + j] = sum;
    pmax[(size_t)blockIdx.x * 128 + j] = mx;
  }
}

// ---- fused: combine readout chunks (both layers) + 2-layer MLP head ----
__global__ __launch_bounds__(128)
void final_mlp(const float* __restrict__ ps1, const float* __restrict__ pm1,
               const float* __restrict__ ps2, const float* __restrict__ pm2,
               const float* __restrict__ fW1, const float* __restrict__ fb1,
               const float* __restrict__ fW2, const float* __restrict__ fb2,
               float* __restrict__ out) {
  __shared__ float xx[256];
  __shared__ float z[128];
  const int g = blockIdx.x, tid = threadIdx.x;
  float s1 = 0.f, m1 = -1e30f, s2 = 0.f, m2 = -1e30f;
#pragma unroll
  for (int c = 0; c < kRChunks; ++c) {
    s1 += ps1[(size_t)(g * kRChunks + c) * 128 + tid];
    m1 = fmaxf(m1, pm1[(size_t)(g * kRChunks + c) * 128 + tid]);
    s2 += ps2[(size_t)(g * kRChunks + c) * 128 + tid];
    m2 = fmaxf(m2, pm2[(size_t)(g * kRChunks + c) * 128 + tid]);
  }
  xx[tid]       = s1 / (float)kK1 + s2 / (float)kK2;
  xx[tid + 128] = m1 + m2;
  __syncthreads();
  float a = fb1[tid];
  for (int k = 0; k < 256; ++k) a += xx[k] * fW1[k * 128 + tid];
  z[tid] = fmaxf(a, 0.0f);
  __syncthreads();
  if (tid < 10) {
    float o = fb2[tid];
    for (int k = 0; k < 128; ++k) o += z[k] * fW2[k * 10 + tid];
    out[g * 10 + tid] = o;
  }
}

}  // namespace

extern "C" void kernel_launch(void* const* d_in, const int* in_sizes, int n_in,
                              void* d_out, int out_size, void* d_ws, size_t ws_size,
                              hipStream_t stream) {
  const float* x   = (const float*)d_in[0];
  const int*   ei  = (const int*)d_in[1];
  const float* Wl1 = (const float*)d_in[3];
  const float* bl1 = (const float*)d_in[4];
  const float* Wr1 = (const float*)d_in[5];
  const float* Wl2 = (const float*)d_in[6];
  const float* bl2 = (const float*)d_in[7];
  const float* Wr2 = (const float*)d_in[8];
  const float* pw1 = (const float*)d_in[9];
  const float* pw2 = (const float*)d_in[10];
  const float* fW1 = (const float*)d_in[11];
  const float* fb1 = (const float*)d_in[12];
  const float* fW2 = (const float*)d_in[13];
  const float* fb2 = (const float*)d_in[14];
  const int* src = ei;
  const int* dst = ei + kE;
  (void)in_sizes; (void)n_in; (void)out_size; (void)ws_size;

  char* wsb = (char*)d_ws;
  size_t off_b = 0;
  auto alloc = [&](size_t bytes) {
    void* p = wsb + off_b;
    off_b += (bytes + 255) & ~(size_t)255;
    return p;
  };
  float* bufA = (float*)alloc((size_t)kM1 * kH * 4);  // mean1 -> mean2
  float* bufB = (float*)alloc((size_t)kM1 * kH * 4);  // h1
  float* bufC = (float*)alloc((size_t)kM2 * kH * 4);  // h2
  int*   deg  = (int*)alloc((size_t)kM1 * 4);
  int*   coff = (int*)alloc((size_t)kM1 * 4);
  int*   ccur = (int*)alloc((size_t)kM1 * 4);
  int*   ent  = (int*)alloc((size_t)kE * 4);
  int2*  ent2 = (int2*)alloc((size_t)kE * 8);
  float* scr  = (float*)alloc((size_t)kM1 * 4);
  int*   kflag= (int*)alloc((size_t)kM1 * 4);
  int2*  aux  = (int2*)alloc((size_t)kM1 * 8);
  int*   perm1= (int*)alloc((size_t)kM2 * 4);
  float* gsc1 = (float*)alloc((size_t)kM2 * 4);
  int*   perm2= (int*)alloc((size_t)kM3 * 4);
  float* gsc2 = (float*)alloc((size_t)kM3 * 4);
  float* psum1= (float*)alloc((size_t)kB * kRChunks * 128 * 4);
  float* pmax1= (float*)alloc((size_t)kB * kRChunks * 128 * 4);
  float* psum2= (float*)alloc((size_t)kB * kRChunks * 128 * 4);
  float* pmax2= (float*)alloc((size_t)kB * kRChunks * 128 * 4);
  ushort* wt1h = (ushort*)alloc((size_t)128 * 256 * 2);
  ushort* wt1l = (ushort*)alloc((size_t)128 * 256 * 2);
  ushort* wt2h = (ushort*)alloc((size_t)128 * 256 * 2);
  ushort* wt2l = (ushort*)alloc((size_t)128 * 256 * 2);
  float* pwn1 = (float*)alloc(128 * 4);
  float* pwn2 = (float*)alloc(128 * 4);

  prep_kernel<<<257, 256, 0, stream>>>(Wl1, Wr1, Wl2, Wr2, pw1, pw2,
                                       wt1h, wt1l, wt2h, wt2l, pwn1, pwn2);

  const int npb1 = kN / 8;             // 128 (8 nodes/block)
  const int npb2 = (kK1 + 7) / 8;      // 103

  // ---------------- layer 1 ----------------
  hipMemsetAsync(deg, 0, (size_t)kM1 * 4, stream);
  deg_kernel<<<kE / 256, 256, 0, stream>>>(dst, deg);
  scan_kernel<<<kB, 1024, 0, stream>>>(deg, kN, coff, ccur);
  fill1_kernel<<<kE / 256, 256, 0, stream>>>(src, dst, ccur, ent);
  gather1_kernel<<<64 * npb1, 256, 0, stream>>>(x, ent, coff, ccur, bufA, kN, npb1);
  sage_gemm_mfma<<<kM1 / 64, 256, 0, stream>>>(bufA, x, nullptr, nullptr,
                                               wt1h, wt1l, bl1, pwn1, bufB, scr);
  rank_kernel<<<kB * 4, 256, 0, stream>>>(scr, kN, kK1, kflag);
  compact_kernel<<<kB, 1024, 0, stream>>>(scr, kflag, kN, kK1, perm1, gsc1, aux);
  readout_part<<<kB * kRChunks, 256, 0, stream>>>(bufB, perm1, gsc1, kK1, psum1, pmax1);

  // ---------------- layer 2 (reuses layer-1 CSR; ent2 folds aux in) ----------------
  ent2prep_kernel<<<kE / 256, 256, 0, stream>>>(ent, aux, ent2);
  gather2_kernel<<<64 * npb2, 256, 0, stream>>>(bufB, ent2, coff, ccur, perm1,
                                                bufA, kK1, npb2);
  sage_gemm_mfma<<<kM2 / 64, 256, 0, stream>>>(bufA, bufB, perm1, gsc1,
                                               wt2h, wt2l, bl2, pwn2, bufC, scr);
  rank_kernel<<<kB * 4, 256, 0, stream>>>(scr, kK1, kK2, kflag);
  compact_kernel<<<kB, 1024, 0, stream>>>(scr, kflag, kK1, kK2, perm2, gsc2, nullptr);
  readout_part<<<kB * kRChunks, 256, 0, stream>>>(bufC, perm2, gsc2, kK2, psum2, pmax2);

  // ---------------- head ----------------
  final_mlp<<<kB, 128, 0, stream>>>(psum1, pmax1, psum2, pmax2,
                                    fW1, fb1, fW2, fb2, (float*)d_out);
}